// Round 2
// baseline (160.580 us; speedup 1.0000x reference)
//
#include <hip/hip_runtime.h>
#include <stdint.h>

// Sampler: temperature -> top-k -> top-p -> softmax -> multinomial (threefry)
// 5-kernel pipeline; rows split across S_CHUNKS blocks for the two passes
// over the 51.5 MB logits matrix (round-1 was 1 block/CU latency-bound).

#define BINS     4096
#define CAP      1024
#define TOPP     0.9f
#define S_CHUNKS 8
#define HBLOCK   256
#define TAILB    512

// Order-preserving float -> uint map (ascending float == ascending uint)
__device__ __forceinline__ unsigned orderKey(float x) {
  unsigned u = __float_as_uint(x);
  return (u & 0x80000000u) ? ~u : (u | 0x80000000u);
}

// JAX threefry2x32 (20 rounds), exact.
__device__ __forceinline__ void threefry2x32(unsigned k0, unsigned k1,
                                             unsigned x0, unsigned x1,
                                             unsigned &o0, unsigned &o1) {
  unsigned k2 = k0 ^ k1 ^ 0x1BD11BDAu;
  x0 += k0; x1 += k1;
#define TFR(rr) { x0 += x1; x1 = (x1 << (rr)) | (x1 >> (32 - (rr))); x1 ^= x0; }
  TFR(13) TFR(15) TFR(26) TFR(6)
  x0 += k1; x1 += k2 + 1u;
  TFR(17) TFR(29) TFR(16) TFR(24)
  x0 += k2; x1 += k0 + 2u;
  TFR(13) TFR(15) TFR(26) TFR(6)
  x0 += k0; x1 += k1 + 3u;
  TFR(17) TFR(29) TFR(16) TFR(24)
  x0 += k1; x1 += k2 + 4u;
  TFR(13) TFR(15) TFR(26) TFR(6)
  x0 += k2; x1 += k0 + 5u;
#undef TFR
  o0 = x0; o1 = x1;
}

// ---- Kernel 1: zero global hist + counters ----
__global__ __launch_bounds__(256) void k_zero(unsigned* __restrict__ p, int n) {
  int i = blockIdx.x * 256 + threadIdx.x;
  int stride = gridDim.x * 256;
  for (; i < n; i += stride) p[i] = 0u;
}

// ---- Kernel 2: per-chunk LDS histogram, merge to global ----
__global__ __launch_bounds__(HBLOCK) void k_hist(
    const float* __restrict__ logits, unsigned* __restrict__ ghist, int V) {
  __shared__ unsigned hist[BINS];
  const int row = blockIdx.y, chunk = blockIdx.x, tid = threadIdx.x;
  const float* __restrict__ rp = logits + (size_t)row * (size_t)V;
  const float4* __restrict__ rp4 = (const float4*)rp;
  const int V4 = V >> 2;
  const int beg = (int)((long long)chunk * V4 / S_CHUNKS);
  const int end = (int)((long long)(chunk + 1) * V4 / S_CHUNKS);

  for (int i = tid; i < BINS; i += HBLOCK) hist[i] = 0u;
  __syncthreads();

  for (int i = beg + tid; i < end; i += HBLOCK) {
    float4 v = rp4[i];
    atomicAdd(&hist[orderKey(v.x) >> 20], 1u);
    atomicAdd(&hist[orderKey(v.y) >> 20], 1u);
    atomicAdd(&hist[orderKey(v.z) >> 20], 1u);
    atomicAdd(&hist[orderKey(v.w) >> 20], 1u);
  }
  if (chunk == S_CHUNKS - 1) {
    for (int i = (V4 << 2) + tid; i < V; i += HBLOCK)
      atomicAdd(&hist[orderKey(rp[i]) >> 20], 1u);
  }
  __syncthreads();

  unsigned* __restrict__ gh = ghist + (size_t)row * BINS;
  for (int i = tid; i < BINS; i += HBLOCK) {
    unsigned c = hist[i];
    if (c) atomicAdd(&gh[i], c);  // device-scope by default (cross-XCD safe)
  }
}

// ---- Kernel 3: per-row suffix scan -> binLo ----
__global__ __launch_bounds__(256) void k_select(
    const unsigned* __restrict__ ghist, const int* __restrict__ topk_ptr,
    int* __restrict__ binLoArr, int V) {
  __shared__ unsigned hist[BINS];
  __shared__ unsigned psum[256];
  const int row = blockIdx.x, tid = threadIdx.x;
  const unsigned* __restrict__ gh = ghist + (size_t)row * BINS;
  for (int i = tid; i < BINS; i += 256) hist[i] = gh[i];
  __syncthreads();

  int k = topk_ptr[0];
  if (k < 1) k = 1;
  if (k > V) k = V;

  const int C = BINS / 256;  // 16
  unsigned s = 0;
#pragma unroll
  for (int j = 0; j < C; ++j) s += hist[tid * C + j];
  psum[tid] = s;
  __syncthreads();

  if (tid == 0) {
    unsigned cum = 0;
    int ch = 0;
    for (int t = 255; t >= 0; --t) {
      if (cum + psum[t] >= (unsigned)k) { ch = t; break; }
      cum += psum[t];
    }
    int bstar = ch * C;
    for (int b = ch * C + C - 1; b >= ch * C; --b) {
      if (cum + hist[b] >= (unsigned)k) { bstar = b; break; }
      cum += hist[b];
    }
    unsigned nCol = cum + hist[bstar];
    int bLo = bstar;
    // tie-safety: one extra bin below when it fits the buffer
    if (bstar > 0 && nCol + hist[bstar - 1] <= (unsigned)CAP) bLo = bstar - 1;
    binLoArr[row] = bLo;
  }
}

// ---- Kernel 4: collect candidates >= bin floor into global buffers ----
__global__ __launch_bounds__(HBLOCK) void k_collect(
    const float* __restrict__ logits, const int* __restrict__ binLoArr,
    unsigned* __restrict__ cnt, float* __restrict__ cvalg,
    int* __restrict__ cidxg, int V) {
  const int row = blockIdx.y, chunk = blockIdx.x, tid = threadIdx.x;
  const unsigned binLo = (unsigned)binLoArr[row];
  const float* __restrict__ rp = logits + (size_t)row * (size_t)V;
  const float4* __restrict__ rp4 = (const float4*)rp;
  const int V4 = V >> 2;
  const int beg = (int)((long long)chunk * V4 / S_CHUNKS);
  const int end = (int)((long long)(chunk + 1) * V4 / S_CHUNKS);
  float* __restrict__ cv = cvalg + (size_t)row * CAP;
  int*   __restrict__ ci = cidxg + (size_t)row * CAP;

  for (int i = beg + tid; i < end; i += HBLOCK) {
    float4 v = rp4[i];
    float vv[4] = {v.x, v.y, v.z, v.w};
#pragma unroll
    for (int c = 0; c < 4; ++c) {
      if ((orderKey(vv[c]) >> 20) >= binLo) {
        unsigned pos = atomicAdd(&cnt[row], 1u);
        if (pos < CAP) { cv[pos] = vv[c]; ci[pos] = (i << 2) + c; }
      }
    }
  }
  if (chunk == S_CHUNKS - 1) {
    for (int i = (V4 << 2) + tid; i < V; i += HBLOCK) {
      float x = rp[i];
      if ((orderKey(x) >> 20) >= binLo) {
        unsigned pos = atomicAdd(&cnt[row], 1u);
        if (pos < CAP) { cv[pos] = x; ci[pos] = i; }
      }
    }
  }
}

// ---- Kernel 5: LDS tail — sort, top-k ties, top-p, softmax, sample ----
__global__ __launch_bounds__(TAILB) void k_tail(
    const unsigned* __restrict__ cnt, const float* __restrict__ cvalg,
    const int* __restrict__ cidxg, const int* __restrict__ topk_ptr,
    int* __restrict__ out, int V) {
  __shared__ float cval[CAP];
  __shared__ int   cidx[CAP];
  __shared__ float sval[CAP];
  __shared__ int   sidx[CAP];
  __shared__ short ord[CAP];
  __shared__ int   s_ns;
  __shared__ int   s_K;
  __shared__ float s_S2;
  __shared__ float s_r;

  const int tid = threadIdx.x;
  const int row = blockIdx.x;

  int k = topk_ptr[0];
  if (k < 1) k = 1;
  if (k > V) k = V;

  int n = (int)cnt[row];
  if (n > CAP) n = CAP;

  const float* __restrict__ cv = cvalg + (size_t)row * CAP;
  const int*   __restrict__ ci = cidxg + (size_t)row * CAP;
  // load + temperature scale (IEEE div, matches ref)
  for (int i = tid; i < n; i += TAILB) {
    cval[i] = cv[i] / 0.8f;
    cidx[i] = ci[i];
  }
  __syncthreads();

  // rank-sort: value desc, index asc (deterministic regardless of arrival order)
  for (int i = tid; i < n; i += TAILB) {
    float v = cval[i];
    int   id = cidx[i];
    int   rk = 0;
    for (int j = 0; j < n; ++j) {
      float vj = cval[j];
      rk += (vj > v) || (vj == v && cidx[j] < id);
    }
    sval[rk] = v;
    sidx[rk] = id;
  }
  __syncthreads();

  // top-k survivor count (keep ties at the k-th value)
  if (tid == 0) {
    int ns = (n < k) ? n : k;
    float kv = sval[ns - 1];
    while (ns < n && sval[ns] == kv) ++ns;
    s_ns = ns;
  }
  __syncthreads();
  const int ns = s_ns;

  // exp(v - max) in parallel (reuse cval as e[])
  const float m = sval[0];
  for (int i = tid; i < ns; i += TAILB) cval[i] = expf(sval[i] - m);
  __syncthreads();

  // top-p keep-prefix + RNG (serial, deterministic order)
  if (tid == 0) {
    float S = 0.f;
    for (int i = 0; i < ns; ++i) S += cval[i];
    float c = 0.f;
    int K = ns;
    for (int i = 0; i < ns; ++i) {
      if (i > 0 && c > TOPP) { K = i; break; }  // remove[i] = cdf[i-1] > p
      c += cval[i] / S;                          // per-element div then add
    }
    float S2 = 0.f;
    for (int i = 0; i < K; ++i) S2 += cval[i];
    s_K = K;
    s_S2 = S2;

    // r = uniform from fold_in(key(0), 1), partitionable threefry path
    unsigned kk0, kk1, o0, o1;
    threefry2x32(0u, 0u, 0u, 1u, kk0, kk1);
    threefry2x32(kk0, kk1, 0u, (unsigned)row, o0, o1);
    unsigned bits = o0 ^ o1;
    float r = __uint_as_float((bits >> 9) | 0x3F800000u) - 1.0f;
    s_r = (r < 0.f) ? 0.f : r;
  }
  __syncthreads();
  const int K = s_K;

  // rank kept tokens by original index
  for (int i = tid; i < K; i += TAILB) {
    int id = sidx[i];
    int rk = 0;
    for (int j = 0; j < K; ++j) rk += (sidx[j] < id);
    ord[rk] = (short)i;
  }
  __syncthreads();

  // inverse-CDF sample in original-index order
  if (tid == 0) {
    const float S2 = s_S2;
    const float rr = s_r;
    float c = 0.f;
    int ans = V;  // matches sum(cdf <= r) when r beyond total mass
    for (int t = 0; t < K; ++t) {
      int i = ord[t];
      c += cval[i] / S2;
      if (c > rr) { ans = sidx[i]; break; }
    }
    out[row] = ans;
  }
}

extern "C" void kernel_launch(void* const* d_in, const int* in_sizes, int n_in,
                              void* d_out, int out_size, void* d_ws, size_t ws_size,
                              hipStream_t stream) {
  const float* logits = (const float*)d_in[0];
  const int*   topk   = (const int*)d_in[1];
  int*         out    = (int*)d_out;
  const int B = out_size;              // 256 rows
  const int V = in_sizes[0] / B;       // 50257

  // workspace layout (bytes)
  char* ws = (char*)d_ws;
  unsigned* ghist  = (unsigned*)ws;                                  // B*BINS u32
  unsigned* cnt    = (unsigned*)(ws + (size_t)B * BINS * 4);         // B u32
  int*      binLo  = (int*)(ws + (size_t)B * BINS * 4 + B * 4);      // B i32
  float*    cvalg  = (float*)(ws + (size_t)B * BINS * 4 + B * 8);    // B*CAP f32
  int*      cidxg  = (int*)(ws + (size_t)B * BINS * 4 + B * 8 +
                            (size_t)B * CAP * 4);                    // B*CAP i32

  const int nzero = B * BINS + B;  // hist + cnt
  hipLaunchKernelGGL(k_zero, dim3((nzero + 255) / 256), dim3(256), 0, stream,
                     ghist, nzero);
  hipLaunchKernelGGL(k_hist, dim3(S_CHUNKS, B), dim3(HBLOCK), 0, stream,
                     logits, ghist, V);
  hipLaunchKernelGGL(k_select, dim3(B), dim3(256), 0, stream,
                     ghist, topk, binLo, V);
  hipLaunchKernelGGL(k_collect, dim3(S_CHUNKS, B), dim3(HBLOCK), 0, stream,
                     logits, binLo, cnt, cvalg, cidxg, V);
  hipLaunchKernelGGL(k_tail, dim3(B), dim3(TAILB), 0, stream,
                     cnt, cvalg, cidxg, topk, out, V);
}

// Round 3
// 135.314 us; speedup vs baseline: 1.1867x; 1.1867x over previous
//
#include <hip/hip_runtime.h>
#include <stdint.h>

// Sampler: temperature -> top-k -> top-p -> softmax -> multinomial (threefry)
// Two kernels, zero global atomics (round-2 post-mortem: device-scope atomic
// hotspot on cnt[row] serialized k_collect at 591 GB/s).
//  k_pass1: per-(row,chunk) block -> LDS hist -> local kth bin (-1 margin)
//           -> collect candidates to a PRIVATE global segment (plain stores).
//           Local top-k superset property: at most k-1 elements anywhere exceed
//           the global kth value, so local top-k \supseteq chunk's share of it.
//  k_tail:  concat segments (~700), LDS hist of candidates -> exact global kth
//           bin, rank-sort ~150 survivors, top-k ties, top-p, softmax, sample.

#define BINS     4096
#define S_CHUNKS 8
#define PB       256              // pass1 block size
#define SEG      256              // per-(row,chunk) candidate capacity
#define CAPT     (S_CHUNKS * SEG) // 2048 tail capacity
#define TB       512              // tail block size
#define TOPP     0.9f

// Order-preserving float -> uint map (ascending float == ascending uint)
__device__ __forceinline__ unsigned orderKey(float x) {
  unsigned u = __float_as_uint(x);
  return (u & 0x80000000u) ? ~u : (u | 0x80000000u);
}

// JAX threefry2x32 (20 rounds), exact.
__device__ __forceinline__ void threefry2x32(unsigned k0, unsigned k1,
                                             unsigned x0, unsigned x1,
                                             unsigned &o0, unsigned &o1) {
  unsigned k2 = k0 ^ k1 ^ 0x1BD11BDAu;
  x0 += k0; x1 += k1;
#define TFR(rr) { x0 += x1; x1 = (x1 << (rr)) | (x1 >> (32 - (rr))); x1 ^= x0; }
  TFR(13) TFR(15) TFR(26) TFR(6)
  x0 += k1; x1 += k2 + 1u;
  TFR(17) TFR(29) TFR(16) TFR(24)
  x0 += k2; x1 += k0 + 2u;
  TFR(13) TFR(15) TFR(26) TFR(6)
  x0 += k0; x1 += k1 + 3u;
  TFR(17) TFR(29) TFR(16) TFR(24)
  x0 += k1; x1 += k2 + 4u;
  TFR(13) TFR(15) TFR(26) TFR(6)
  x0 += k2; x1 += k0 + 5u;
#undef TFR
  o0 = x0; o1 = x1;
}

// ---- Kernel 1: local hist + local-top-k collect into private segments ----
__global__ __launch_bounds__(PB) void k_pass1(
    const float* __restrict__ logits, const int* __restrict__ topk_ptr,
    int* __restrict__ scnt, float* __restrict__ svals, int* __restrict__ sidxs,
    int V) {
  __shared__ unsigned hist[BINS];   // 16 KB
  __shared__ unsigned psum[PB];
  __shared__ float    lval[SEG];
  __shared__ int      lidx[SEG];
  __shared__ unsigned lcnt;
  __shared__ int      s_b;

  const int row = blockIdx.y, chunk = blockIdx.x, tid = threadIdx.x;
  const float* __restrict__ rp = logits + (size_t)row * (size_t)V;
  const float4* __restrict__ rp4 = (const float4*)rp;
  const int V4 = V >> 2;
  const int beg = (int)((long long)chunk * V4 / S_CHUNKS);
  const int end = (int)((long long)(chunk + 1) * V4 / S_CHUNKS);
  const bool last = (chunk == S_CHUNKS - 1);
  const int rembeg = V4 << 2;

  for (int i = tid; i < BINS; i += PB) hist[i] = 0u;
  if (tid == 0) lcnt = 0u;
  __syncthreads();

  for (int i = beg + tid; i < end; i += PB) {
    float4 v = rp4[i];
    atomicAdd(&hist[orderKey(v.x) >> 20], 1u);
    atomicAdd(&hist[orderKey(v.y) >> 20], 1u);
    atomicAdd(&hist[orderKey(v.z) >> 20], 1u);
    atomicAdd(&hist[orderKey(v.w) >> 20], 1u);
  }
  if (last)
    for (int i = rembeg + tid; i < V; i += PB)
      atomicAdd(&hist[orderKey(rp[i]) >> 20], 1u);
  __syncthreads();

  int k = topk_ptr[0];
  if (k < 1) k = 1;
  if (k > V) k = V;
  const int ec = (end - beg) * 4 + (last ? (V - rembeg) : 0);
  if (k > ec) k = ec;

  const int C = BINS / PB;  // 16
  {
    unsigned s = 0;
#pragma unroll
    for (int j = 0; j < C; ++j) s += hist[tid * C + j];
    psum[tid] = s;
  }
  __syncthreads();
  if (tid == 0) {
    unsigned cum = 0;
    int ch = 0;
    for (int t = PB - 1; t >= 0; --t) {
      if (cum + psum[t] >= (unsigned)k) { ch = t; break; }
      cum += psum[t];
    }
    int bstar = ch * C;
    for (int b = ch * C + C - 1; b >= ch * C; --b) {
      if (cum + hist[b] >= (unsigned)k) { bstar = b; break; }
      cum += hist[b];
    }
    s_b = (bstar > 0) ? bstar - 1 : 0;  // one-bin margin (temp-division collapse)
  }
  __syncthreads();

  const unsigned bLo = (unsigned)s_b;
  for (int i = beg + tid; i < end; i += PB) {  // re-scan: L2/L3-warm
    float4 v = rp4[i];
    float vv[4] = {v.x, v.y, v.z, v.w};
#pragma unroll
    for (int c = 0; c < 4; ++c) {
      if ((orderKey(vv[c]) >> 20) >= bLo) {
        unsigned pos = atomicAdd(&lcnt, 1u);  // LDS atomic only
        if (pos < SEG) { lval[pos] = vv[c]; lidx[pos] = (i << 2) + c; }
      }
    }
  }
  if (last)
    for (int i = rembeg + tid; i < V; i += PB) {
      float x = rp[i];
      if ((orderKey(x) >> 20) >= bLo) {
        unsigned pos = atomicAdd(&lcnt, 1u);
        if (pos < SEG) { lval[pos] = x; lidx[pos] = i; }
      }
    }
  __syncthreads();

  int n = (lcnt > SEG) ? SEG : (int)lcnt;
  const int sb = row * S_CHUNKS + chunk;
  if (tid == 0) scnt[sb] = n;
  float* __restrict__ ov = svals + (size_t)sb * SEG;
  int*   __restrict__ oi = sidxs + (size_t)sb * SEG;
  for (int i = tid; i < n; i += PB) { ov[i] = lval[i]; oi[i] = lidx[i]; }
}

// ---- Kernel 2: merge segments, exact top-k/top-p/softmax/sample ----
__global__ __launch_bounds__(TB) void k_tail(
    const int* __restrict__ scnt, const float* __restrict__ svals,
    const int* __restrict__ sidxs, const int* __restrict__ topk_ptr,
    int* __restrict__ out, int V) {
  __shared__ float    cval[CAPT];  // 8 KB  (raw cands -> sorted scaled)
  __shared__ int      cidx[CAPT];  // 8 KB
  __shared__ float    sval[CAPT];  // 8 KB  (scaled survivors -> e[])
  __shared__ int      sidx[CAPT];  // 8 KB
  __shared__ short    ord[CAPT];   // 4 KB
  __shared__ unsigned hist[BINS];  // 16 KB
  __shared__ unsigned psum[TB];    // 2 KB
  __shared__ int      s_off[S_CHUNKS + 1];
  __shared__ unsigned s_mc;
  __shared__ int      s_bg, s_ns, s_K;
  __shared__ float    s_S2, s_r;

  const int row = blockIdx.x, tid = threadIdx.x;
  int k = topk_ptr[0];
  if (k < 1) k = 1;
  if (k > V) k = V;

  if (tid == 0) {
    int off = 0;
    for (int c = 0; c < S_CHUNKS; ++c) { s_off[c] = off; off += scnt[row * S_CHUNKS + c]; }
    s_off[S_CHUNKS] = off;
    s_mc = 0u;
  }
  for (int i = tid; i < BINS; i += TB) hist[i] = 0u;
  __syncthreads();

  const int n = s_off[S_CHUNKS];
  for (int c = 0; c < S_CHUNKS; ++c) {
    const int cn = s_off[c + 1] - s_off[c];
    const int o  = s_off[c];
    const float* __restrict__ sv = svals + (size_t)(row * S_CHUNKS + c) * SEG;
    const int*   __restrict__ si = sidxs + (size_t)(row * S_CHUNKS + c) * SEG;
    for (int i = tid; i < cn; i += TB) {
      float x = sv[i];
      cval[o + i] = x;
      cidx[o + i] = si[i];
      atomicAdd(&hist[orderKey(x) >> 20], 1u);
    }
  }
  __syncthreads();

  // exact global kth bin from candidate hist (complete at/above bin(v*))
  const int kk = (k > n) ? n : k;
  {
    const int C = BINS / TB;  // 8
    unsigned s = 0;
#pragma unroll
    for (int j = 0; j < C; ++j) s += hist[tid * C + j];
    psum[tid] = s;
  }
  __syncthreads();
  if (tid == 0) {
    const int C = BINS / TB;
    unsigned cum = 0;
    int ch = 0;
    for (int t = TB - 1; t >= 0; --t) {
      if (cum + psum[t] >= (unsigned)kk) { ch = t; break; }
      cum += psum[t];
    }
    int bstar = ch * C;
    for (int b = ch * C + C - 1; b >= ch * C; --b) {
      if (cum + hist[b] >= (unsigned)kk) { bstar = b; break; }
      cum += hist[b];
    }
    s_bg = (bstar > 0) ? bstar - 1 : 0;  // margin for temp-division collapse
  }
  __syncthreads();

  // compact survivors, apply temperature (IEEE div, matches ref)
  const unsigned bg = (unsigned)s_bg;
  for (int i = tid; i < n; i += TB) {
    float x = cval[i];
    if ((orderKey(x) >> 20) >= bg) {
      unsigned pos = atomicAdd(&s_mc, 1u);
      sval[pos] = x / 0.8f;
      sidx[pos] = cidx[i];
    }
  }
  __syncthreads();
  const int m = (int)s_mc;

  // rank-sort survivors (scaled desc, index asc) -> cval/cidx
  for (int i = tid; i < m; i += TB) {
    float v = sval[i];
    int   id = sidx[i];
    int   rk = 0;
    for (int j = 0; j < m; ++j) {
      float vj = sval[j];
      rk += (vj > v) || (vj == v && sidx[j] < id);
    }
    cval[rk] = v;
    cidx[rk] = id;
  }
  __syncthreads();

  // top-k survivor count (keep ties at the k-th value)
  if (tid == 0) {
    int ns = (m < kk) ? m : kk;
    float kv = cval[ns - 1];
    while (ns < m && cval[ns] == kv) ++ns;
    s_ns = ns;
  }
  __syncthreads();
  const int ns = s_ns;

  // e = exp(v - max)
  const float mx = cval[0];
  for (int i = tid; i < ns; i += TB) sval[i] = expf(cval[i] - mx);
  __syncthreads();

  // top-p keep-prefix + RNG (serial, deterministic order)
  if (tid == 0) {
    float S = 0.f;
    for (int i = 0; i < ns; ++i) S += sval[i];
    float c = 0.f;
    int K = ns;
    for (int i = 0; i < ns; ++i) {
      if (i > 0 && c > TOPP) { K = i; break; }  // remove[i] = cdf[i-1] > p
      c += sval[i] / S;
    }
    float S2 = 0.f;
    for (int i = 0; i < K; ++i) S2 += sval[i];
    s_K = K;
    s_S2 = S2;

    // r = uniform from fold_in(key(0), 1), partitionable threefry path
    unsigned kk0, kk1, o0, o1;
    threefry2x32(0u, 0u, 0u, 1u, kk0, kk1);
    threefry2x32(kk0, kk1, 0u, (unsigned)row, o0, o1);
    unsigned bits = o0 ^ o1;
    float r = __uint_as_float((bits >> 9) | 0x3F800000u) - 1.0f;
    s_r = (r < 0.f) ? 0.f : r;
  }
  __syncthreads();
  const int K = s_K;

  // rank kept tokens by original index
  for (int i = tid; i < K; i += TB) {
    int id = cidx[i];
    int rk = 0;
    for (int j = 0; j < K; ++j) rk += (cidx[j] < id);
    ord[rk] = (short)i;
  }
  __syncthreads();

  // inverse-CDF sample in original-index order
  if (tid == 0) {
    const float S2 = s_S2;
    const float rr = s_r;
    float c = 0.f;
    int ans = V;  // matches sum(cdf <= r) when r beyond total mass
    for (int t = 0; t < K; ++t) {
      int i = ord[t];
      c += sval[i] / S2;
      if (c > rr) { ans = cidx[i]; break; }
    }
    out[row] = ans;
  }
}

extern "C" void kernel_launch(void* const* d_in, const int* in_sizes, int n_in,
                              void* d_out, int out_size, void* d_ws, size_t ws_size,
                              hipStream_t stream) {
  const float* logits = (const float*)d_in[0];
  const int*   topk   = (const int*)d_in[1];
  int*         out    = (int*)d_out;
  const int B = out_size;              // 256 rows
  const int V = in_sizes[0] / B;       // 50257

  // workspace layout (no zeroing needed — every slot we read is written first)
  char* ws = (char*)d_ws;
  int*   scnt  = (int*)ws;                                           // B*S u32
  float* svals = (float*)(ws + (size_t)B * S_CHUNKS * 4);            // B*S*SEG f32
  int*   sidxs = (int*)(ws + (size_t)B * S_CHUNKS * 4 +
                        (size_t)B * S_CHUNKS * SEG * 4);             // B*S*SEG i32

  hipLaunchKernelGGL(k_pass1, dim3(S_CHUNKS, B), dim3(PB), 0, stream,
                     logits, topk, scnt, svals, sidxs, V);
  hipLaunchKernelGGL(k_tail, dim3(B), dim3(TB), 0, stream,
                     scnt, svals, sidxs, topk, out, V);
}